// Round 6
// baseline (221.936 us; speedup 1.0000x reference)
//
#include <hip/hip_runtime.h>
#include <cstdint>

#define D_MODEL 1024
#define BATCH 4
#define SEQ 4096
#define M_TOT (BATCH*SEQ)   // 16384

#define BM 128
#define BNG 64              // per-gate N tile
#define BK 64
#define NKT (D_MODEL/BK)    // 16

#define XS_BYTES (BM*BK*2)           // 16384: 128 rows x 128 B
#define WG_BYTES (BNG*BK*2)          // 8192:  64 n-rows x 128 B per gate
#define SMEM_BYTES (XS_BYTES + 3*WG_BYTES)   // 40960 -> 4 blocks/CU

#define NCHUNK 64
#define CHUNK 64

typedef __bf16 bf16x8 __attribute__((ext_vector_type(8)));
typedef float f32x4 __attribute__((ext_vector_type(4)));
typedef unsigned short u16x8 __attribute__((ext_vector_type(8)));

static __device__ __forceinline__ unsigned short f2bf(float f) {
    unsigned int u = __float_as_uint(f);
    return (unsigned short)((u + 0x7fffu + ((u >> 16) & 1u)) >> 16);
}

// ---------------- convert x (fp32 -> bf16), 8 elems/thread ----------------
__global__ void k_convert_x(const float* __restrict__ x, unsigned short* __restrict__ xb) {
    int i = blockIdx.x * 256 + threadIdx.x;
    const float4* p = (const float4*)x;
    float4 v0 = p[2*i], v1 = p[2*i+1];
    u16x8 r;
    r[0] = f2bf(v0.x); r[1] = f2bf(v0.y); r[2] = f2bf(v0.z); r[3] = f2bf(v0.w);
    r[4] = f2bf(v1.x); r[5] = f2bf(v1.y); r[6] = f2bf(v1.z); r[7] = f2bf(v1.w);
    *(u16x8*)(xb + (size_t)i * 8) = r;
}

// ---------------- transpose + convert W: wt[g][n][k] = W_g[k][n] ----------
__global__ void k_transpose_w(const float* __restrict__ Wf, const float* __restrict__ Wi,
                              const float* __restrict__ Wb, unsigned short* __restrict__ wt) {
    __shared__ float tile[32][33];
    int g = blockIdx.z;
    const float* W = (g == 0) ? Wf : (g == 1) ? Wi : Wb;
    int n0 = blockIdx.x * 32, k0 = blockIdx.y * 32;
    int tx = threadIdx.x, ty = threadIdx.y;   // 32 x 8
    for (int j = 0; j < 4; ++j)
        tile[ty + j*8][tx] = W[(size_t)(k0 + ty + j*8) * D_MODEL + n0 + tx];
    __syncthreads();
    for (int j = 0; j < 4; ++j) {
        int n = n0 + ty + j*8;
        wt[(size_t)g * D_MODEL * D_MODEL + (size_t)n * D_MODEL + k0 + tx] = f2bf(tile[tx][ty + j*8]);
    }
}

// ---------------- fused 3-gate GEMM + epilogue ----------------------------
// 4 waves, wave tile 64x32 per gate; 40 KiB single-buffered LDS -> 4
// blocks/CU (16 waves/CU: m114 implicit overlap); m97 2-barrier structure;
// global_load_lds w16 with inverse-swizzled source; XOR-swizzled ds_read.
#define GL16(gp, lp) \
    __builtin_amdgcn_global_load_lds((const __attribute__((address_space(1))) void*)(gp), \
                                     (__attribute__((address_space(3))) void*)(lp), 16, 0, 0)

__launch_bounds__(256, 4)
__global__ void k_gemm_gates(const unsigned short* __restrict__ xb, const unsigned short* __restrict__ wt,
                             const float* __restrict__ bfv, const float* __restrict__ biv,
                             const float* __restrict__ bbv,
                             float* __restrict__ a_out, float* __restrict__ bg_out) {
    extern __shared__ char smem[];
    const int tid  = threadIdx.x;
    const int wave = tid >> 6;            // 0..3
    const int lane = tid & 63;
    const int lr = lane & 15, lg = lane >> 4;
    const int m0 = blockIdx.x * BM;
    const int n0 = blockIdx.y * BNG;
    const int wrow = (wave >> 1) * 64;    // 0 or 64
    const int wcol = (wave & 1) * 32;     // 0 or 32

    // ---- staging addressing: 10 issues x 256 thr x 16B = 40 KiB/tile -----
    // issue j covers LDS bytes j*4096 + tid*16 -> row j*32 + (tid>>3),
    // col chunk (tid&7)*16 (linear dest); global source col is swizzled.
    const int srl = tid >> 3;                                // 0..31, srl&7 == (tid>>3)&7
    const int scb = ((tid & 7) * 16) ^ ((srl & 7) << 4);     // swizzled byte col
    const size_t aoff = (size_t)(m0 + srl) * D_MODEL + (scb >> 1);
    const size_t boff = (size_t)(n0 + srl) * D_MODEL + (scb >> 1);  // srl<32 < 64 rows/gate

#define STAGE(kt) do { \
        const int _ko = (kt) * BK; \
        char* _d = smem + wave*1024; \
        GL16(xb + aoff + 0*32*D_MODEL + _ko, _d + 0*4096); \
        GL16(xb + aoff + 1*32*D_MODEL + _ko, _d + 1*4096); \
        GL16(xb + aoff + 2*32*D_MODEL + _ko, _d + 2*4096); \
        GL16(xb + aoff + 3*32*D_MODEL + _ko, _d + 3*4096); \
        _Pragma("unroll") \
        for (int g = 0; g < 3; ++g) { \
            const unsigned short* _s = wt + (size_t)g*D_MODEL*D_MODEL + boff + _ko; \
            char* _db = _d + XS_BYTES + g*WG_BYTES; \
            GL16(_s + 0*32*D_MODEL, _db + 0*4096); \
            GL16(_s + 1*32*D_MODEL, _db + 1*4096); \
        } \
    } while (0)

    f32x4 acc[3][4][2] = {};
    const int sxor = (lr & 7) << 4;   // read-side swizzle (row&7 == lr&7 for all rows read)

    STAGE(0);
    __syncthreads();

    for (int kt = 0; kt < NKT; ++kt) {
        // ---- compute tile kt from LDS ------------------------------------
        bf16x8 af[2][4];
        #pragma unroll
        for (int kk = 0; kk < 2; ++kk) {
            const int ko = (kk*64 + lg*16) ^ sxor;
            #pragma unroll
            for (int mi = 0; mi < 4; ++mi)
                af[kk][mi] = *(const bf16x8*)(smem + (wrow + mi*16 + lr)*128 + ko);
        }
        #pragma unroll
        for (int g = 0; g < 3; ++g) {
            #pragma unroll
            for (int ni = 0; ni < 2; ++ni) {
                const char* brow = smem + XS_BYTES + g*WG_BYTES + (wcol + ni*16 + lr)*128;
                bf16x8 b0 = *(const bf16x8*)(brow + ((0*64 + lg*16) ^ sxor));
                bf16x8 b1 = *(const bf16x8*)(brow + ((1*64 + lg*16) ^ sxor));
                #pragma unroll
                for (int mi = 0; mi < 4; ++mi) {
                    acc[g][mi][ni] = __builtin_amdgcn_mfma_f32_16x16x32_bf16(
                        af[0][mi], b0, acc[g][mi][ni], 0, 0, 0);
                    acc[g][mi][ni] = __builtin_amdgcn_mfma_f32_16x16x32_bf16(
                        af[1][mi], b1, acc[g][mi][ni], 0, 0, 0);
                }
            }
        }
        __syncthreads();                       // all waves done reading tile kt
        if (kt + 1 < NKT) {
            STAGE(kt + 1);                     // overwrite LDS with tile kt+1
            __syncthreads();                   // staged data visible
        }
    }

    // epilogue: C/D layout: col = lane&15, row = (lane>>4)*4 + reg
    #pragma unroll
    for (int ni = 0; ni < 2; ++ni) {
        const int col = n0 + wcol + ni*16 + lr;
        const float vbf = bfv[col], vbi = biv[col], vbb = bbv[col];
        #pragma unroll
        for (int mi = 0; mi < 4; ++mi) {
            #pragma unroll
            for (int r = 0; r < 4; ++r) {
                const int row = m0 + wrow + mi*16 + lg*4 + r;
                const float zf = acc[0][mi][ni][r] + vbf;
                const float zi = acc[1][mi][ni][r] + vbi;
                const float zb = (acc[2][mi][ni][r] + vbb) * 0.03125f;  // /sqrt(1024)
                const float a  = 1.0f / (1.0f + __expf(zf));    // 1 - sigmoid(zf)
                const float ig = 1.0f / (1.0f + __expf(-zi));
                const size_t o = (size_t)row * D_MODEL + col;
                a_out[o]  = a;
                bg_out[o] = ig * zb;
            }
        }
    }
#undef STAGE
}

// ---------------- scan pass 1: per-chunk aggregates -----------------------
__global__ void k_chunk_local(const float* __restrict__ a, const float* __restrict__ bg,
                              float* __restrict__ Ac, float* __restrict__ Bc) {
    const int d = (blockIdx.x & 3) * 256 + threadIdx.x;
    const int c = (blockIdx.x >> 2) & 63;
    const int b = blockIdx.x >> 8;
    const size_t base = ((size_t)b * SEQ + (size_t)c * CHUNK) * D_MODEL + d;
    float A = 1.0f, Bv = 0.0f;
    for (int t = 0; t < CHUNK; ++t) {
        const float av = a[base + (size_t)t * D_MODEL];
        const float bv = bg[base + (size_t)t * D_MODEL];
        A *= av;
        Bv = fmaf(av, Bv, bv);
    }
    const size_t o = ((size_t)b * NCHUNK + c) * D_MODEL + d;
    Ac[o] = A;
    Bc[o] = Bv;
}

// ---------------- scan pass 2: exclusive prefix over chunks ---------------
__global__ void k_chunk_prefix(const float* __restrict__ Ac, const float* __restrict__ Bc,
                               float* __restrict__ H) {
    const int d = (blockIdx.x & 3) * 256 + threadIdx.x;
    const int b = blockIdx.x >> 2;
    float h = 0.0f;
    for (int c = 0; c < NCHUNK; ++c) {
        const size_t o = ((size_t)b * NCHUNK + c) * D_MODEL + d;
        H[o] = h;                     // state entering chunk c
        h = fmaf(Ac[o], h, Bc[o]);
    }
}

// ---------------- scan pass 3: apply (io holds bg in, h out) --------------
__global__ void k_apply(const float* __restrict__ a, float* io, const float* __restrict__ H) {
    const int d = (blockIdx.x & 3) * 256 + threadIdx.x;
    const int c = (blockIdx.x >> 2) & 63;
    const int b = blockIdx.x >> 8;
    const size_t base = ((size_t)b * SEQ + (size_t)c * CHUNK) * D_MODEL + d;
    float h = H[((size_t)b * NCHUNK + c) * D_MODEL + d];
    for (int t = 0; t < CHUNK; ++t) {
        const size_t o = base + (size_t)t * D_MODEL;
        const float bv = io[o];       // read bg before overwrite (same thread)
        h = fmaf(a[o], h, bv);
        io[o] = h;
    }
}

extern "C" void kernel_launch(void* const* d_in, const int* in_sizes, int n_in,
                              void* d_out, int out_size, void* d_ws, size_t ws_size,
                              hipStream_t stream) {
    const float* x   = (const float*)d_in[0];
    const float* Wf  = (const float*)d_in[1];
    const float* bfv = (const float*)d_in[2];
    const float* Wi  = (const float*)d_in[3];
    const float* biv = (const float*)d_in[4];
    const float* Wb  = (const float*)d_in[5];
    const float* bbv = (const float*)d_in[6];
    float* out = (float*)d_out;

    char* ws = (char*)d_ws;
    float*          a_buf = (float*)ws;                             // 64 MiB
    unsigned short* xb    = (unsigned short*)(ws + (64ull << 20));  // 32 MiB
    unsigned short* wt    = (unsigned short*)(ws + (96ull << 20));  // 6 MiB
    float* Ac = (float*)(ws + (64ull << 20));   // reuse xb region after GEMM
    float* Bc = (float*)(ws + (65ull << 20));
    float* Hb = (float*)(ws + (66ull << 20));
    float* bg_buf = out;   // d_out doubles as bg scratch; k_apply overwrites in place

    hipFuncSetAttribute((const void*)k_gemm_gates,
                        hipFuncAttributeMaxDynamicSharedMemorySize, SMEM_BYTES);

    hipLaunchKernelGGL(k_convert_x, dim3((M_TOT * D_MODEL / 8) / 256), dim3(256), 0, stream, x, xb);
    hipLaunchKernelGGL(k_transpose_w, dim3(32, 32, 3), dim3(32, 8), 0, stream, Wf, Wi, Wb, wt);
    hipLaunchKernelGGL(k_gemm_gates, dim3(M_TOT / BM, D_MODEL / BNG), dim3(256), SMEM_BYTES, stream,
                       xb, wt, bfv, biv, bbv, a_buf, bg_buf);
    hipLaunchKernelGGL(k_chunk_local, dim3(BATCH * NCHUNK * (D_MODEL / 256)), dim3(256), 0, stream,
                       a_buf, bg_buf, Ac, Bc);
    hipLaunchKernelGGL(k_chunk_prefix, dim3(BATCH * (D_MODEL / 256)), dim3(256), 0, stream,
                       Ac, Bc, Hb);
    hipLaunchKernelGGL(k_apply, dim3(BATCH * NCHUNK * (D_MODEL / 256)), dim3(256), 0, stream,
                       a_buf, bg_buf, Hb);
}

// Round 7
// 202.857 us; speedup vs baseline: 1.0941x; 1.0941x over previous
//
#include <hip/hip_runtime.h>
#include <cstdint>

#define D_MODEL 1024
#define BATCH 4
#define SEQ 4096
#define M_TOT (BATCH*SEQ)   // 16384

#define BM 256
#define BN 128              // per gate
#define BK 64
#define NKT (D_MODEL/BK)    // 16

#define XS_BYTES (BM*BK*2)                 // 32768
#define WG_BYTES (BN*BK*2)                 // 16384 per gate
#define TILE_BYTES (XS_BYTES + 3*WG_BYTES) // 81920
#define SMEM_BYTES (2*TILE_BYTES)          // 163840 = full LDS pool, 1 block/CU

#define NCHUNK 64
#define CHUNK 64

typedef __bf16 bf16x8 __attribute__((ext_vector_type(8)));
typedef float f32x4 __attribute__((ext_vector_type(4)));
typedef unsigned short u16x8 __attribute__((ext_vector_type(8)));

static __device__ __forceinline__ unsigned short f2bf(float f) {
    unsigned int u = __float_as_uint(f);
    return (unsigned short)((u + 0x7fffu + ((u >> 16) & 1u)) >> 16);
}

// ---------------- convert x (fp32 -> bf16), 8 elems/thread ----------------
__global__ void k_convert_x(const float* __restrict__ x, unsigned short* __restrict__ xb) {
    int i = blockIdx.x * 256 + threadIdx.x;
    const float4* p = (const float4*)x;
    float4 v0 = p[2*i], v1 = p[2*i+1];
    u16x8 r;
    r[0] = f2bf(v0.x); r[1] = f2bf(v0.y); r[2] = f2bf(v0.z); r[3] = f2bf(v0.w);
    r[4] = f2bf(v1.x); r[5] = f2bf(v1.y); r[6] = f2bf(v1.z); r[7] = f2bf(v1.w);
    *(u16x8*)(xb + (size_t)i * 8) = r;
}

// ---------------- transpose + convert W: wt[g][n][k] = W_g[k][n] ----------
__global__ void k_transpose_w(const float* __restrict__ Wf, const float* __restrict__ Wi,
                              const float* __restrict__ Wb, unsigned short* __restrict__ wt) {
    __shared__ float tile[32][33];
    int g = blockIdx.z;
    const float* W = (g == 0) ? Wf : (g == 1) ? Wi : Wb;
    int n0 = blockIdx.x * 32, k0 = blockIdx.y * 32;
    int tx = threadIdx.x, ty = threadIdx.y;   // 32 x 8
    for (int j = 0; j < 4; ++j)
        tile[ty + j*8][tx] = W[(size_t)(k0 + ty + j*8) * D_MODEL + n0 + tx];
    __syncthreads();
    for (int j = 0; j < 4; ++j) {
        int n = n0 + ty + j*8;
        wt[(size_t)g * D_MODEL * D_MODEL + (size_t)n * D_MODEL + k0 + tx] = f2bf(tile[tx][ty + j*8]);
    }
}

// ---------------- fused 3-gate GEMM + epilogue + chunk-aggregate ----------
// 8 waves (2 row x 4 col), per-wave 128x32 per gate: LDS bytes/FLOP 0.0178
// (-31% vs prior). 160 KiB double-buffered LDS, plain 2-barrier structure.
// Epilogue computes per-chunk scan aggregates in-register (pass1 fused).
#define GL16(gp, lp) \
    __builtin_amdgcn_global_load_lds((const __attribute__((address_space(1))) void*)(gp), \
                                     (__attribute__((address_space(3))) void*)(lp), 16, 0, 0)

__launch_bounds__(512, 2)
__global__ void k_gemm_gates(const unsigned short* __restrict__ xb, const unsigned short* __restrict__ wt,
                             const float* __restrict__ bfv, const float* __restrict__ biv,
                             const float* __restrict__ bbv,
                             float* __restrict__ a_out, float* __restrict__ bg_out,
                             float* __restrict__ Ac, float* __restrict__ Bc) {
    extern __shared__ char smem[];
    const int tid  = threadIdx.x;
    const int wave = tid >> 6;            // 0..7
    const int lane = tid & 63;
    const int lr = lane & 15, lg = lane >> 4;
    const int m0 = blockIdx.x * BM;
    const int n0 = blockIdx.y * BN;
    const int wr = wave >> 2;             // 0..1 -> rows wr*128
    const int wc = wave & 3;              // 0..3 -> cols wc*32
    const int wrow = wr * 128;
    const int wcol = wc * 32;

    // ---- staging: 10 GL16 issues x 512 thr x 16B = 80 KiB/tile ----------
    const int srow = tid >> 3;                               // 0..63
    const int scb  = ((tid & 7) * 16) ^ ((srow & 7) << 4);   // inverse-swizzled src col
    const size_t a0 = (size_t)(m0 +   0 + srow) * D_MODEL + (scb >> 1);
    const size_t a1 = (size_t)(m0 +  64 + srow) * D_MODEL + (scb >> 1);
    const size_t a2 = (size_t)(m0 + 128 + srow) * D_MODEL + (scb >> 1);
    const size_t a3 = (size_t)(m0 + 192 + srow) * D_MODEL + (scb >> 1);
    const size_t b0 = (size_t)(n0 +   0 + srow) * D_MODEL + (scb >> 1);
    const size_t b1 = (size_t)(n0 +  64 + srow) * D_MODEL + (scb >> 1);
    const unsigned short* w0 = wt;
    const unsigned short* w1 = wt + 1ull*D_MODEL*D_MODEL;
    const unsigned short* w2 = wt + 2ull*D_MODEL*D_MODEL;

#define STAGE(bufsel, kt) do { \
        const size_t _k = (size_t)(kt) * BK; \
        char* _d = smem + (bufsel)*TILE_BYTES + wave*1024; \
        GL16(xb + a0 + _k, _d + 0*8192); \
        GL16(xb + a1 + _k, _d + 1*8192); \
        GL16(xb + a2 + _k, _d + 2*8192); \
        GL16(xb + a3 + _k, _d + 3*8192); \
        GL16(w0 + b0 + _k, _d + 4*8192); \
        GL16(w0 + b1 + _k, _d + 5*8192); \
        GL16(w1 + b0 + _k, _d + 6*8192); \
        GL16(w1 + b1 + _k, _d + 7*8192); \
        GL16(w2 + b0 + _k, _d + 8*8192); \
        GL16(w2 + b1 + _k, _d + 9*8192); \
    } while (0)

    f32x4 acc[3][8][2] = {};
    const int sxor = (lr & 7) << 4;   // read-side swizzle (row&7 == lr&7)

    STAGE(0, 0);
    __syncthreads();

    for (int kt = 0; kt < NKT; ++kt) {
        if (kt + 1 < NKT) STAGE((kt + 1) & 1, kt + 1);
        const char* tb = smem + (kt & 1) * TILE_BYTES;
        #pragma unroll
        for (int kk = 0; kk < 2; ++kk) {
            const int ko = (kk*64 + lg*16) ^ sxor;
            bf16x8 bw[3][2];
            #pragma unroll
            for (int g = 0; g < 3; ++g)
                #pragma unroll
                for (int ni = 0; ni < 2; ++ni)
                    bw[g][ni] = *(const bf16x8*)(tb + XS_BYTES + g*WG_BYTES +
                                                 (wcol + ni*16 + lr)*128 + ko);
            #pragma unroll
            for (int mi = 0; mi < 8; ++mi) {
                bf16x8 afr = *(const bf16x8*)(tb + (wrow + mi*16 + lr)*128 + ko);
                #pragma unroll
                for (int g = 0; g < 3; ++g)
                    #pragma unroll
                    for (int ni = 0; ni < 2; ++ni)
                        acc[g][mi][ni] = __builtin_amdgcn_mfma_f32_16x16x32_bf16(
                            afr, bw[g][ni], acc[g][mi][ni], 0, 0, 0);
            }
        }
        __syncthreads();   // drains staged loads; all waves done reading buf
    }

    // ---- epilogue: gates + a/bg writes + fused chunk aggregates ----------
    // C/D layout: col = lane&15, row = (lane>>4)*4 + reg.
    // Wave wr's 128 rows = 2 chunks (half = mi>>2); within chunk, time index
    // = (mi&3)*16 + lg*4 + r. Per 4-row segment fold, then ordered lg-tree,
    // then serial quarter compose.
    #pragma unroll
    for (int ni = 0; ni < 2; ++ni) {
        const int col = n0 + wcol + ni*16 + lr;
        const float vbf = bfv[col], vbi = biv[col], vbb = bbv[col];
        float sA[2][4], sB[2][4];
        #pragma unroll
        for (int mi = 0; mi < 8; ++mi) {
            float Ap = 1.0f, Bp = 0.0f;
            #pragma unroll
            for (int r = 0; r < 4; ++r) {
                const int row = m0 + wrow + mi*16 + lg*4 + r;
                const float zf = acc[0][mi][ni][r] + vbf;
                const float zi = acc[1][mi][ni][r] + vbi;
                const float zb = (acc[2][mi][ni][r] + vbb) * 0.03125f;  // /sqrt(1024)
                const float a  = 1.0f / (1.0f + __expf(zf));    // 1 - sigmoid(zf)
                const float ig = 1.0f / (1.0f + __expf(-zi));
                const float bg = ig * zb;
                const size_t o = (size_t)row * D_MODEL + col;
                a_out[o]  = a;
                bg_out[o] = bg;
                Bp = fmaf(a, Bp, bg);   // time order: r ascending
                Ap *= a;
            }
            sA[mi >> 2][mi & 3] = Ap;
            sB[mi >> 2][mi & 3] = Bp;
        }
        #pragma unroll
        for (int half = 0; half < 2; ++half) {
            float CA = 1.0f, CB = 0.0f;
            #pragma unroll
            for (int q = 0; q < 4; ++q) {
                float A = sA[half][q], B = sB[half][q];
                // ordered 4-lane (lg) tree: rows q*16 + lg*4 + r
                float Ao = __shfl_xor(A, 16), Bo = __shfl_xor(B, 16);
                float B1 = (lg & 1) ? fmaf(A, Bo, B) : fmaf(Ao, B, Bo);
                float A1 = A * Ao;
                Ao = __shfl_xor(A1, 32); Bo = __shfl_xor(B1, 32);
                float B2 = (lg & 2) ? fmaf(A1, Bo, B1) : fmaf(Ao, B1, Bo);
                float A2 = A1 * Ao;
                // compose running chunk with quarter q (q ascending in time)
                CB = fmaf(A2, CB, B2);
                CA = CA * A2;
            }
            if (lg == 0) {
                const int chG = blockIdx.x * 4 + wr * 2 + half;  // global chunk id
                Ac[(size_t)chG * D_MODEL + col] = CA;
                Bc[(size_t)chG * D_MODEL + col] = CB;
            }
        }
    }
#undef STAGE
}

// ---------------- scan pass 2: exclusive prefix over chunks ---------------
__global__ void k_chunk_prefix(const float* __restrict__ Ac, const float* __restrict__ Bc,
                               float* __restrict__ H) {
    const int d = (blockIdx.x & 3) * 256 + threadIdx.x;
    const int b = blockIdx.x >> 2;
    float h = 0.0f;
    for (int c = 0; c < NCHUNK; ++c) {
        const size_t o = ((size_t)b * NCHUNK + c) * D_MODEL + d;
        H[o] = h;                     // state entering chunk c
        h = fmaf(Ac[o], h, Bc[o]);
    }
}

// ---------------- scan pass 3: apply (io holds bg in, h out) --------------
__global__ void k_apply(const float* __restrict__ a, float* io, const float* __restrict__ H) {
    const int d = (blockIdx.x & 3) * 256 + threadIdx.x;
    const int c = (blockIdx.x >> 2) & 63;
    const int b = blockIdx.x >> 8;
    const size_t base = ((size_t)b * SEQ + (size_t)c * CHUNK) * D_MODEL + d;
    float h = H[((size_t)b * NCHUNK + c) * D_MODEL + d];
    for (int t = 0; t < CHUNK; ++t) {
        const size_t o = base + (size_t)t * D_MODEL;
        const float bv = io[o];       // read bg before overwrite (same thread)
        h = fmaf(a[o], h, bv);
        io[o] = h;
    }
}

extern "C" void kernel_launch(void* const* d_in, const int* in_sizes, int n_in,
                              void* d_out, int out_size, void* d_ws, size_t ws_size,
                              hipStream_t stream) {
    const float* x   = (const float*)d_in[0];
    const float* Wf  = (const float*)d_in[1];
    const float* bfv = (const float*)d_in[2];
    const float* Wi  = (const float*)d_in[3];
    const float* biv = (const float*)d_in[4];
    const float* Wb  = (const float*)d_in[5];
    const float* bbv = (const float*)d_in[6];
    float* out = (float*)d_out;

    char* ws = (char*)d_ws;
    float*          a_buf = (float*)ws;                             // 0..64 MiB
    unsigned short* xb    = (unsigned short*)(ws + (64ull << 20));  // 64..96 MiB
    unsigned short* wt    = (unsigned short*)(ws + (96ull << 20));  // 96..102 MiB
    float* Ac = (float*)(ws + (102ull << 20));  // 1 MiB (written during GEMM)
    float* Bc = (float*)(ws + (103ull << 20));  // 1 MiB
    float* Hb = (float*)(ws + (64ull << 20));   // reuse xb region after GEMM
    float* bg_buf = out;   // d_out doubles as bg scratch; k_apply overwrites

    hipFuncSetAttribute((const void*)k_gemm_gates,
                        hipFuncAttributeMaxDynamicSharedMemorySize, SMEM_BYTES);

    hipLaunchKernelGGL(k_convert_x, dim3((M_TOT * D_MODEL / 8) / 256), dim3(256), 0, stream, x, xb);
    hipLaunchKernelGGL(k_transpose_w, dim3(32, 32, 3), dim3(32, 8), 0, stream, Wf, Wi, Wb, wt);
    hipLaunchKernelGGL(k_gemm_gates, dim3(M_TOT / BM, D_MODEL / BN), dim3(512), SMEM_BYTES, stream,
                       xb, wt, bfv, biv, bbv, a_buf, bg_buf, Ac, Bc);
    hipLaunchKernelGGL(k_chunk_prefix, dim3(BATCH * (D_MODEL / 256)), dim3(256), 0, stream,
                       Ac, Bc, Hb);
    hipLaunchKernelGGL(k_apply, dim3(BATCH * NCHUNK * (D_MODEL / 256)), dim3(256), 0, stream,
                       a_buf, bg_buf, Hb);
}

// Round 8
// 163.667 us; speedup vs baseline: 1.3560x; 1.2395x over previous
//
#include <hip/hip_runtime.h>
#include <cstdint>

#define D_MODEL 1024
#define BATCH 4
#define SEQ 4096
#define M_TOT (BATCH*SEQ)   // 16384

#define BM 128
#define BN 128
#define BK 64
#define NKT (D_MODEL/BK)    // 16

#define XS_BYTES 16384              // 128 rows x 128 B (64 bf16 k)
#define WG_BYTES 16384              // per gate: 128 n-rows x 128 B
#define TILE_BYTES (XS_BYTES + 3*WG_BYTES)   // 64 KiB
#define SMEM_BYTES (2*TILE_BYTES)            // 128 KiB double-buffered

#define NCHUNK 64
#define CHUNK 64

typedef __bf16 bf16x8 __attribute__((ext_vector_type(8)));
typedef float f32x4 __attribute__((ext_vector_type(4)));
typedef unsigned short u16x8 __attribute__((ext_vector_type(8)));

static __device__ __forceinline__ unsigned short f2bf(float f) {
    unsigned int u = __float_as_uint(f);
    return (unsigned short)((u + 0x7fffu + ((u >> 16) & 1u)) >> 16);
}
static __device__ __forceinline__ float ubf(unsigned short u) {
    return __uint_as_float((unsigned int)u << 16);
}

// ---------------- convert x (fp32 -> bf16), 8 elems/thread ----------------
__global__ void k_convert_x(const float* __restrict__ x, unsigned short* __restrict__ xb) {
    int i = blockIdx.x * 256 + threadIdx.x;
    const float4* p = (const float4*)x;
    float4 v0 = p[2*i], v1 = p[2*i+1];
    u16x8 r;
    r[0] = f2bf(v0.x); r[1] = f2bf(v0.y); r[2] = f2bf(v0.z); r[3] = f2bf(v0.w);
    r[4] = f2bf(v1.x); r[5] = f2bf(v1.y); r[6] = f2bf(v1.z); r[7] = f2bf(v1.w);
    *(u16x8*)(xb + (size_t)i * 8) = r;
}

// ---------------- transpose + convert W: wt[g][n][k] = W_g[k][n] ----------
__global__ void k_transpose_w(const float* __restrict__ Wf, const float* __restrict__ Wi,
                              const float* __restrict__ Wb, unsigned short* __restrict__ wt) {
    __shared__ float tile[32][33];
    int g = blockIdx.z;
    const float* W = (g == 0) ? Wf : (g == 1) ? Wi : Wb;
    int n0 = blockIdx.x * 32, k0 = blockIdx.y * 32;
    int tx = threadIdx.x, ty = threadIdx.y;   // 32 x 8
    for (int j = 0; j < 4; ++j)
        tile[ty + j*8][tx] = W[(size_t)(k0 + ty + j*8) * D_MODEL + n0 + tx];
    __syncthreads();
    for (int j = 0; j < 4; ++j) {
        int n = n0 + ty + j*8;
        wt[(size_t)g * D_MODEL * D_MODEL + (size_t)n * D_MODEL + k0 + tx] = f2bf(tile[tx][ty + j*8]);
    }
}

// ---------------- fused 3-gate GEMM + epilogue + chunk-aggregate ----------
// Round-2 proven structure (135.6 us): 8 waves, 64x32 wave tile per gate,
// 128 KiB dbuf LDS, plain 2-barrier loop, global_load_lds w16 with
// inverse-swizzled source, XOR-swizzled ds_read_b128 (0 conflicts).
// Epilogue: writes f,bg as bf16 and computes per-chunk scan aggregates
// in-register (scan pass 1 fused; round-7-verified tree).
#define GL16(gp, lp) \
    __builtin_amdgcn_global_load_lds((const __attribute__((address_space(1))) void*)(gp), \
                                     (__attribute__((address_space(3))) void*)(lp), 16, 0, 0)

__launch_bounds__(512, 2)
__global__ void k_gemm_gates(const unsigned short* __restrict__ xb, const unsigned short* __restrict__ wt,
                             const float* __restrict__ bfv, const float* __restrict__ biv,
                             const float* __restrict__ bbv,
                             unsigned short* __restrict__ f_out, unsigned short* __restrict__ bg_out,
                             float* __restrict__ Ac, float* __restrict__ Bc) {
    extern __shared__ char smem[];
    const int tid  = threadIdx.x;
    const int wave = tid >> 6;
    const int lane = tid & 63;
    const int lr = lane & 15, lg = lane >> 4;
    const int m0 = blockIdx.x * BM;
    const int n0 = blockIdx.y * BN;
    const int wr = wave >> 2;             // 0..1
    const int wrow = wr * 64;
    const int wcol = (wave & 3) * 32;     // 0,32,64,96

    // ---- staging source pointers (8 issues x 512 thr x 16B = 64 KiB/tile)
    const int srow = tid >> 3;                                  // 0..63
    const int scb  = ((tid & 7) * 16) ^ ((srow & 7) << 4);      // swizzled byte col
    const unsigned short* s0 = xb + (size_t)(m0 + srow)      * D_MODEL + (scb >> 1);
    const unsigned short* s1 = xb + (size_t)(m0 + 64 + srow) * D_MODEL + (scb >> 1);
    const unsigned short* s2 = wt + 0ull*D_MODEL*D_MODEL + (size_t)(n0 + srow)      * D_MODEL + (scb >> 1);
    const unsigned short* s3 = wt + 0ull*D_MODEL*D_MODEL + (size_t)(n0 + 64 + srow) * D_MODEL + (scb >> 1);
    const unsigned short* s4 = wt + 1ull*D_MODEL*D_MODEL + (size_t)(n0 + srow)      * D_MODEL + (scb >> 1);
    const unsigned short* s5 = wt + 1ull*D_MODEL*D_MODEL + (size_t)(n0 + 64 + srow) * D_MODEL + (scb >> 1);
    const unsigned short* s6 = wt + 2ull*D_MODEL*D_MODEL + (size_t)(n0 + srow)      * D_MODEL + (scb >> 1);
    const unsigned short* s7 = wt + 2ull*D_MODEL*D_MODEL + (size_t)(n0 + 64 + srow) * D_MODEL + (scb >> 1);

#define STAGE(bufsel) do { \
        char* _b = smem + (bufsel)*TILE_BYTES + wave*1024; \
        GL16(s0, _b + 0*8192); GL16(s1, _b + 1*8192); \
        GL16(s2, _b + 2*8192); GL16(s3, _b + 3*8192); \
        GL16(s4, _b + 4*8192); GL16(s5, _b + 5*8192); \
        GL16(s6, _b + 6*8192); GL16(s7, _b + 7*8192); \
        s0 += BK; s1 += BK; s2 += BK; s3 += BK; \
        s4 += BK; s5 += BK; s6 += BK; s7 += BK; \
    } while (0)

    f32x4 acc[3][4][2] = {};
    const int sxor = (lr & 7) << 4;   // read-side swizzle

    STAGE(0);
    __syncthreads();

    for (int kt = 0; kt < NKT; ++kt) {
        if (kt + 1 < NKT) STAGE((kt + 1) & 1);

        const char* tb = smem + (kt & 1) * TILE_BYTES;
        #pragma unroll
        for (int kk = 0; kk < 2; ++kk) {
            const int ko = (kk*64 + lg*16) ^ sxor;
            bf16x8 af[2];
            bf16x8 bw[3][2];
            #pragma unroll
            for (int mi = 0; mi < 2; ++mi)
                af[mi] = *(const bf16x8*)(tb + (wrow + mi*16 + lr)*128 + ko);
            #pragma unroll
            for (int g = 0; g < 3; ++g)
                #pragma unroll
                for (int ni = 0; ni < 2; ++ni)
                    bw[g][ni] = *(const bf16x8*)(tb + XS_BYTES + g*WG_BYTES +
                                                 (wcol + ni*16 + lr)*128 + ko);
            // NOTE round-2 used mi in 0..2? no: af[2] covers 32 rows; full 64
            // rows handled by second pair below (mirrors round-2's 4-mi loop
            // split into two af reads of 2 to cap live regs)
            #pragma unroll
            for (int g = 0; g < 3; ++g)
                #pragma unroll
                for (int mi = 0; mi < 2; ++mi)
                    #pragma unroll
                    for (int ni = 0; ni < 2; ++ni)
                        acc[g][mi][ni] = __builtin_amdgcn_mfma_f32_16x16x32_bf16(
                            af[mi], bw[g][ni], acc[g][mi][ni], 0, 0, 0);
            bf16x8 af2[2];
            #pragma unroll
            for (int mi = 0; mi < 2; ++mi)
                af2[mi] = *(const bf16x8*)(tb + (wrow + (mi+2)*16 + lr)*128 + ko);
            #pragma unroll
            for (int g = 0; g < 3; ++g)
                #pragma unroll
                for (int mi = 0; mi < 2; ++mi)
                    #pragma unroll
                    for (int ni = 0; ni < 2; ++ni)
                        acc[g][mi+2][ni] = __builtin_amdgcn_mfma_f32_16x16x32_bf16(
                            af2[mi], bw[g][ni], acc[g][mi+2][ni], 0, 0, 0);
        }
        __syncthreads();
    }

    // ---- epilogue: gates -> bf16 f/bg + fused per-chunk aggregates -------
    // C/D layout: col = lane&15, row = (lane>>4)*4 + reg. Wave's 64 rows =
    // one chunk; time idx = mi*16 + lg*4 + r.
    #pragma unroll
    for (int ni = 0; ni < 2; ++ni) {
        const int col = n0 + wcol + ni*16 + lr;
        const float vbf = bfv[col], vbi = biv[col], vbb = bbv[col];
        float qA[4], qB[4];
        #pragma unroll
        for (int mi = 0; mi < 4; ++mi) {
            float Ap = 1.0f, Bp = 0.0f;
            #pragma unroll
            for (int r = 0; r < 4; ++r) {
                const int row = m0 + wrow + mi*16 + lg*4 + r;
                const float zf = acc[0][mi][ni][r] + vbf;
                const float zi = acc[1][mi][ni][r] + vbi;
                const float zb = (acc[2][mi][ni][r] + vbb) * 0.03125f;  // /sqrt(1024)
                const float fg = 1.0f / (1.0f + __expf(-zf));   // forget gate f
                const float ig = 1.0f / (1.0f + __expf(-zi));
                const unsigned short fu  = f2bf(fg);
                const unsigned short bgu = f2bf(ig * zb);
                const float a_r  = 1.0f - ubf(fu);    // use ROUNDED values so
                const float bg_r = ubf(bgu);          // aggregates match apply
                const size_t o = (size_t)row * D_MODEL + col;
                f_out[o]  = fu;
                bg_out[o] = bgu;
                Bp = fmaf(a_r, Bp, bg_r);   // time order: r ascending
                Ap *= a_r;
            }
            qA[mi] = Ap; qB[mi] = Bp;
        }
        // ordered 4-lane (lg) tree over 16-row quarters, then serial compose
        float CA = 1.0f, CB = 0.0f;
        #pragma unroll
        for (int q = 0; q < 4; ++q) {
            float A = qA[q], B = qB[q];
            float Ao = __shfl_xor(A, 16), Bo = __shfl_xor(B, 16);
            float B1 = (lg & 1) ? fmaf(A, Bo, B) : fmaf(Ao, B, Bo);
            float A1 = A * Ao;
            Ao = __shfl_xor(A1, 32); Bo = __shfl_xor(B1, 32);
            float B2 = (lg & 2) ? fmaf(A1, Bo, B1) : fmaf(Ao, B1, Bo);
            float A2 = A1 * Ao;
            CB = fmaf(A2, CB, B2);
            CA = CA * A2;
        }
        if (lg == 0) {
            const int chG = blockIdx.x * 2 + wr;     // global chunk id
            Ac[(size_t)chG * D_MODEL + col] = CA;
            Bc[(size_t)chG * D_MODEL + col] = CB;
        }
    }
#undef STAGE
}

// ---------------- scan pass 2: exclusive prefix over chunks ---------------
__global__ void k_chunk_prefix(const float* __restrict__ Ac, const float* __restrict__ Bc,
                               float* __restrict__ H) {
    const int d = (blockIdx.x & 3) * 256 + threadIdx.x;
    const int b = blockIdx.x >> 2;
    float h = 0.0f;
    for (int c = 0; c < NCHUNK; ++c) {
        const size_t o = ((size_t)b * NCHUNK + c) * D_MODEL + d;
        H[o] = h;                     // state entering chunk c
        h = fmaf(Ac[o], h, Bc[o]);
    }
}

// ---------------- scan pass 3: apply (bf16 f/bg in, fp32 h out) -----------
__global__ void k_apply(const unsigned short* __restrict__ f, const unsigned short* __restrict__ bg,
                        const float* __restrict__ H, float* __restrict__ out) {
    const int d0 = (blockIdx.x & 1) * 512 + threadIdx.x * 2;
    const int c = (blockIdx.x >> 1) & 63;
    const int b = blockIdx.x >> 7;
    const size_t base = ((size_t)b * SEQ + (size_t)c * CHUNK) * D_MODEL + d0;
    const size_t hoff = ((size_t)b * NCHUNK + c) * D_MODEL + d0;
    float h0 = H[hoff], h1 = H[hoff + 1];
    for (int t = 0; t < CHUNK; ++t) {
        const size_t o = base + (size_t)t * D_MODEL;
        const unsigned int fv = *(const unsigned int*)(f + o);    // f[d0], f[d0+1]
        const unsigned int gv = *(const unsigned int*)(bg + o);
        const float a0 = 1.0f - __uint_as_float(fv << 16);
        const float a1 = 1.0f - __uint_as_float(fv & 0xffff0000u);
        const float b0 = __uint_as_float(gv << 16);
        const float b1 = __uint_as_float(gv & 0xffff0000u);
        h0 = fmaf(a0, h0, b0);
        h1 = fmaf(a1, h1, b1);
        *(float2*)(out + o) = make_float2(h0, h1);
    }
}

extern "C" void kernel_launch(void* const* d_in, const int* in_sizes, int n_in,
                              void* d_out, int out_size, void* d_ws, size_t ws_size,
                              hipStream_t stream) {
    const float* x   = (const float*)d_in[0];
    const float* Wf  = (const float*)d_in[1];
    const float* bfv = (const float*)d_in[2];
    const float* Wi  = (const float*)d_in[3];
    const float* biv = (const float*)d_in[4];
    const float* Wb  = (const float*)d_in[5];
    const float* bbv = (const float*)d_in[6];
    float* out = (float*)d_out;

    char* ws = (char*)d_ws;
    unsigned short* fbuf  = (unsigned short*)ws;                    // 0..32 MiB
    unsigned short* bgbuf = (unsigned short*)(ws + (32ull << 20));  // 32..64 MiB
    unsigned short* xb    = (unsigned short*)(ws + (64ull << 20));  // 64..96 MiB
    unsigned short* wt    = (unsigned short*)(ws + (96ull << 20));  // 96..102 MiB
    float* Ac = (float*)(ws + (102ull << 20));  // 1 MiB (written during GEMM)
    float* Bc = (float*)(ws + (103ull << 20));  // 1 MiB
    float* Hb = (float*)(ws + (64ull << 20));   // reuse xb region after GEMM

    hipFuncSetAttribute((const void*)k_gemm_gates,
                        hipFuncAttributeMaxDynamicSharedMemorySize, SMEM_BYTES);

    hipLaunchKernelGGL(k_convert_x, dim3((M_TOT * D_MODEL / 8) / 256), dim3(256), 0, stream, x, xb);
    hipLaunchKernelGGL(k_transpose_w, dim3(32, 32, 3), dim3(32, 8), 0, stream, Wf, Wi, Wb, wt);
    hipLaunchKernelGGL(k_gemm_gates, dim3(M_TOT / BM, D_MODEL / BN), dim3(512), SMEM_BYTES, stream,
                       xb, wt, bfv, biv, bbv, fbuf, bgbuf, Ac, Bc);
    hipLaunchKernelGGL(k_chunk_prefix, dim3(BATCH * (D_MODEL / 256)), dim3(256), 0, stream,
                       Ac, Bc, Hb);
    hipLaunchKernelGGL(k_apply, dim3(BATCH * NCHUNK * 2), dim3(256), 0, stream,
                       fbuf, bgbuf, Hb, out);
}